// Round 12
// baseline (184.558 us; speedup 1.0000x reference)
//
#include <hip/hip_runtime.h>
#include <hip/hip_bf16.h>

#define SS 2048
#define DD 512
#define HWIN 128

typedef __bf16 bf16x8 __attribute__((ext_vector_type(8)));
typedef unsigned short u16x8 __attribute__((ext_vector_type(8)));
typedef float f32x4 __attribute__((ext_vector_type(4)));

__device__ __forceinline__ unsigned short f2bf(float x) {
    unsigned u = __builtin_bit_cast(unsigned, x);
    return (unsigned short)((u + 0x7fffu + ((u >> 16) & 1u)) >> 16);
}
__device__ __forceinline__ float bf2f(unsigned short s) {
    unsigned u = ((unsigned)s) << 16;
    return __builtin_bit_cast(float, u);
}
__device__ __forceinline__ void split_bf(float x, unsigned short& h, unsigned short& l) {
    h = f2bf(x);
    l = f2bf(x - bf2f(h));
}
__device__ __forceinline__ void split8(float4 f0, float4 f1, u16x8& h, u16x8& l) {
    const float vals[8] = {f0.x, f0.y, f0.z, f0.w, f1.x, f1.y, f1.z, f1.w};
    #pragma unroll
    for (int i = 0; i < 8; ++i) {
        unsigned short hh, ll;
        split_bf(vals[i], hh, ll);
        h[i] = hh;
        l[i] = ll;
    }
}
__device__ __forceinline__ f32x4 mfma16(u16x8 a, u16x8 b, f32x4 c) {
    return __builtin_amdgcn_mfma_f32_16x16x32_bf16(
        __builtin_bit_cast(bf16x8, a), __builtin_bit_cast(bf16x8, b), c, 0, 0, 0);
}
// Direct global -> LDS DMA, 16 B per lane (dest = wave-uniform base + lane*16).
__device__ __forceinline__ void gload16(const unsigned short* g, unsigned short* l) {
    __builtin_amdgcn_global_load_lds(
        (const __attribute__((address_space(1))) unsigned int*)g,
        (__attribute__((address_space(3))) unsigned int*)l, 16, 0, 0);
}

// ---------------------------------------------------------------------------
// Cast Wq,Wk,Wv -> WP (paired hi/lo bf16) and Wo -> WoP.
// ---------------------------------------------------------------------------
__global__ __launch_bounds__(256) void castW(
    const float* __restrict__ wq, const float* __restrict__ wk,
    const float* __restrict__ wv, const float* __restrict__ wo,
    unsigned short* __restrict__ WP, unsigned short* __restrict__ WoP)
{
    const size_t e0 = ((size_t)blockIdx.x * 256 + threadIdx.x) * 8;
    const float* src; size_t off; unsigned short* dst;
    if      (e0 < 262144) { src = wq; off = e0;          dst = WP + 2 * e0; }
    else if (e0 < 524288) { src = wk; off = e0 - 262144; dst = WP + 2 * e0; }
    else if (e0 < 786432) { src = wv; off = e0 - 524288; dst = WP + 2 * e0; }
    else                  { src = wo; off = e0 - 786432; dst = WoP + 2 * (e0 - 786432); }
    u16x8 h, l;
    split8(*(const float4*)(src + off), *(const float4*)(src + off + 4), h, l);
    *(u16x8*)(dst)     = h;
    *(u16x8*)(dst + 8) = l;
}

// ---------------------------------------------------------------------------
// proj GEMM, 64x64 tile, BK=32, grid 1536 (6 blocks/CU): C = A@W.T + bias.
// Wave w owns m-tile w (16 rows) x 4 n-tiles. Staging: lane L handles
// row L&15, k-chunk (L>>4)*8 of its wave's tile — identical to the MFMA
// fragment mapping, so LDS slot L is read back by lane L (fragment-contig).
// A fp32 split in-register; W paired bf16 DMA'd. z==2 writes V transposed.
// XCD swizzle: all 8 nblk-siblings of (z,mblk) share gid%8.
// ---------------------------------------------------------------------------
__global__ __launch_bounds__(256) void proj_gemm(
    const float* __restrict__ q, const float* __restrict__ k, const float* __restrict__ v,
    const unsigned short* __restrict__ WP,
    const float* __restrict__ bq, const float* __restrict__ bk, const float* __restrict__ bv,
    unsigned short* __restrict__ base,
    unsigned short* __restrict__ VTH, unsigned short* __restrict__ VTL)
{
    const int gid = blockIdx.x;            // 0..1535
    const int r8 = gid & 7;
    const int nblk = (gid >> 3) & 7;
    const int u = (gid >> 6) * 8 + r8;     // 0..191
    const int z = u >> 6, mblk = u & 63;

    const float* A = (z == 0) ? q : ((z == 1) ? k : v);
    const unsigned short* Wp = WP + (size_t)z * 524288;
    const float* bias = (z == 0) ? bq : ((z == 1) ? bk : bv);
    unsigned short* OH = base + (size_t)z * 4194304;
    unsigned short* OL = OH + 2097152;

    const int m0 = mblk * 64, n0 = nblk * 64;

    __shared__ unsigned short Ah[4 * 64 * 8], Al[4 * 64 * 8];  // [tile][lane][8]
    __shared__ unsigned short Bh[4 * 64 * 8], Bl[4 * 64 * 8];

    const int tid = threadIdx.x, wave = tid >> 6, lane = tid & 63;
    const int lm = lane & 15, lq = lane >> 4;
    const int kb = lq * 8;

    f32x4 acc[4] = {};

    const int arow = m0 + wave * 16 + lm;   // this wave's A row for staging
    const int brow = n0 + wave * 16 + lm;   // this wave's W row for staging
    unsigned short* aDh = &Ah[(wave * 64 + lane) * 8];
    unsigned short* aDl = &Al[(wave * 64 + lane) * 8];
    unsigned short* bDh = &Bh[(wave * 64 + lane) * 8];
    unsigned short* bDl = &Bl[(wave * 64 + lane) * 8];

    for (int k0 = 0; k0 < 512; k0 += 32) {
        const float* pa = A + (size_t)arow * 512 + k0 + kb;
        const float4 fa0 = *(const float4*)pa, fa1 = *(const float4*)(pa + 4);

        __syncthreads();                 // prev iteration's frag reads done
        {
            u16x8 hh, ll;
            split8(fa0, fa1, hh, ll);
            *(u16x8*)aDh = hh;
            *(u16x8*)aDl = ll;
        }
        {
            const unsigned short* pw = Wp + 2 * ((size_t)brow * 512 + k0 + kb);
            gload16(pw,     bDh);
            gload16(pw + 8, bDl);
        }
        __syncthreads();                 // staging visible (lds + vmcnt)

        const u16x8 a_h = *(const u16x8*)&Ah[(wave * 64 + lane) * 8];
        const u16x8 a_l = *(const u16x8*)&Al[(wave * 64 + lane) * 8];
        #pragma unroll
        for (int j = 0; j < 4; ++j) {
            const u16x8 b_h = *(const u16x8*)&Bh[(j * 64 + lane) * 8];
            const u16x8 b_l = *(const u16x8*)&Bl[(j * 64 + lane) * 8];
            acc[j] = mfma16(a_h, b_h, acc[j]);
            acc[j] = mfma16(a_h, b_l, acc[j]);
            acc[j] = mfma16(a_l, b_h, acc[j]);
        }
    }

    #pragma unroll
    for (int j = 0; j < 4; ++j) {
        const int col = n0 + j * 16 + lm;
        const float bv_ = bias[col];
        #pragma unroll
        for (int r = 0; r < 4; ++r) {
            const int row = m0 + wave * 16 + lq * 4 + r;
            const float vv = acc[j][r] + bv_;
            unsigned short hh, ll;
            split_bf(vv, hh, ll);
            if (z == 2) {
                const size_t vix =
                    (((size_t)(row >> 11) * 8 + (col >> 6)) * 64 + (col & 63)) * 2048
                    + (row & 2047);
                VTH[vix] = hh;
                VTL[vix] = ll;
            } else {
                OH[(size_t)row * 512 + col] = hh;
                OL[(size_t)row * 512 + col] = ll;
            }
        }
    }
}

// ---------------------------------------------------------------------------
// out GEMM, BK=64: 64x64 tile, grid 512, full DMA staging (R11 config).
// ---------------------------------------------------------------------------
__global__ __launch_bounds__(256) void out_gemm(
    const unsigned short* __restrict__ XHg, const unsigned short* __restrict__ XLg,
    const unsigned short* __restrict__ WoP, const float* __restrict__ bo,
    float* __restrict__ O)
{
    const int gid = blockIdx.x;            // 0..511
    const int rr = gid & 7, hi = gid >> 3;
    const int nblk = hi & 7, mhi = hi >> 3;
    const int mblk = mhi * 8 + rr;         // 0..63
    const int m0 = mblk * 64, n0 = nblk * 64;

    __shared__ unsigned short Ah[8 * 64 * 8], Al[8 * 64 * 8];  // [s*4+tm][lane][8]
    __shared__ unsigned short Bh[8 * 64 * 8], Bl[8 * 64 * 8];

    const int tid = threadIdx.x, wave = tid >> 6, lane = tid & 63;
    const int lm = lane & 15, lq = lane >> 4;
    const int kb = lq * 8;

    f32x4 acc[4] = {};

    const int arow = m0 + wave * 16 + lm;
    const int brow = n0 + wave * 16 + lm;

    for (int k0 = 0; k0 < 512; k0 += 64) {
        __syncthreads();
        #pragma unroll
        for (int s = 0; s < 2; ++s) {
            gload16(XHg + (size_t)arow * 512 + k0 + s * 32 + kb,
                    &Ah[((s * 4 + wave) * 64 + lane) * 8]);
            gload16(XLg + (size_t)arow * 512 + k0 + s * 32 + kb,
                    &Al[((s * 4 + wave) * 64 + lane) * 8]);
            const unsigned short* pw = WoP + 2 * ((size_t)brow * 512 + k0 + s * 32 + kb);
            gload16(pw,     &Bh[((s * 4 + wave) * 64 + lane) * 8]);
            gload16(pw + 8, &Bl[((s * 4 + wave) * 64 + lane) * 8]);
        }
        __syncthreads();

        #pragma unroll
        for (int s = 0; s < 2; ++s) {
            const u16x8 a_h = *(const u16x8*)&Ah[((s * 4 + wave) * 64 + lane) * 8];
            const u16x8 a_l = *(const u16x8*)&Al[((s * 4 + wave) * 64 + lane) * 8];
            #pragma unroll
            for (int j = 0; j < 4; ++j) {
                const u16x8 b_h = *(const u16x8*)&Bh[((s * 4 + j) * 64 + lane) * 8];
                const u16x8 b_l = *(const u16x8*)&Bl[((s * 4 + j) * 64 + lane) * 8];
                acc[j] = mfma16(a_h, b_h, acc[j]);
                acc[j] = mfma16(a_h, b_l, acc[j]);
                acc[j] = mfma16(a_l, b_h, acc[j]);
            }
        }
    }

    #pragma unroll
    for (int j = 0; j < 4; ++j) {
        const int col = n0 + j * 16 + lm;
        const float bv_ = bo[col];
        #pragma unroll
        for (int r = 0; r < 4; ++r) {
            const int row = m0 + wave * 16 + lq * 4 + r;
            O[(size_t)row * 512 + col] = acc[j][r] + bv_;
        }
    }
}

// ---------------------------------------------------------------------------
// V column sums from VT layout (contiguous in s). Two-stage.
// ---------------------------------------------------------------------------
__global__ __launch_bounds__(256) void vsum_stage1(
    const unsigned short* __restrict__ VTH, const unsigned short* __restrict__ VTL,
    float* __restrict__ partial)
{
    const int bh = blockIdx.x, c = blockIdx.y;
    const int t = threadIdx.x, dd = t & 63, g = t >> 6;
    __shared__ float p[4][64];
    const size_t rb = ((size_t)bh * 64 + dd) * 2048 + c * 64 + g * 16;
    const u16x8 h0 = *(const u16x8*)(VTH + rb), h1 = *(const u16x8*)(VTH + rb + 8);
    const u16x8 l0 = *(const u16x8*)(VTL + rb), l1 = *(const u16x8*)(VTL + rb + 8);
    float acc = 0.f;
    #pragma unroll
    for (int i = 0; i < 8; ++i) acc += bf2f(h0[i]) + bf2f(l0[i]);
    #pragma unroll
    for (int i = 0; i < 8; ++i) acc += bf2f(h1[i]) + bf2f(l1[i]);
    p[g][dd] = acc;
    __syncthreads();
    if (t < 64)
        partial[((size_t)bh * 32 + c) * 64 + t] =
            p[0][t] + p[1][t] + p[2][t] + p[3][t];
}

__global__ __launch_bounds__(64) void vsum_stage2(
    const float* __restrict__ partial, float* __restrict__ VS)
{
    const int bh = blockIdx.x, dd = threadIdx.x;
    float acc = 0.f;
    #pragma unroll 8
    for (int c = 0; c < 32; ++c)
        acc += partial[((size_t)bh * 32 + c) * 64 + dd];
    VS[bh * 64 + dd] = acc;
}

// ---------------------------------------------------------------------------
// Split-bf16 MFMA sliding-window attention with clamp-and-mask DMA staging
// (R11 config): K and V^T fragments DMA directly global->LDS; per-lane j
// clamped to [0,2047] (clamped values only multiply masked w=0 / P=0).
//   x = [ sum_win (e^s - 1) v + VS ] / ( 2048 + sum_win (e^s - 1) )
// ---------------------------------------------------------------------------
__global__ __launch_bounds__(256) void attn_mfma(
    const unsigned short* __restrict__ QH, const unsigned short* __restrict__ QL,
    const unsigned short* __restrict__ KH, const unsigned short* __restrict__ KL,
    const unsigned short* __restrict__ VTH, const unsigned short* __restrict__ VTL,
    const float* __restrict__ VS,
    unsigned short* __restrict__ XH, unsigned short* __restrict__ XL)
{
    const int dblk = blockIdx.x;
    const int bhi = dblk >> 8, blow = dblk & 255;
    const int xblk = blow >> 3, rrs = blow & 7;
    const int bh = bhi * 8 + rrs;        // 0..15
    const int h = bh & 7, b = bh >> 3;
    const int i0 = xblk * 64;
    const int tid = threadIdx.x, wave = tid >> 6, lane = tid & 63;
    const int lm = lane & 15, lq = lane >> 4;
    const int kb = lq * 8;

    __shared__ unsigned short KfH[8 * 64 * 8], KfL[8 * 64 * 8];  // [js*2+c][lane][8]
    __shared__ unsigned short VfH[8 * 64 * 8], VfL[8 * 64 * 8];  // [s4*2+c][lane][8]
    __shared__ unsigned short Swh[64][72], Swl[64][72];          // [q][j]

    const size_t qoff = ((size_t)(b * SS + i0 + wave * 16 + lm)) * DD + h * 64 + kb;
    const u16x8 aQ0h = *(const u16x8*)(QH + qoff);
    const u16x8 aQ0l = *(const u16x8*)(QL + qoff);
    const u16x8 aQ1h = *(const u16x8*)(QH + qoff + 32);
    const u16x8 aQ1l = *(const u16x8*)(QL + qoff + 32);

    f32x4 oacc[4] = {};
    float dacc[4] = {0.f, 0.f, 0.f, 0.f};

    unsigned short* kDh0 = &KfH[((wave * 2 + 0) * 64 + lane) * 8];
    unsigned short* kDh1 = &KfH[((wave * 2 + 1) * 64 + lane) * 8];
    unsigned short* kDl0 = &KfL[((wave * 2 + 0) * 64 + lane) * 8];
    unsigned short* kDl1 = &KfL[((wave * 2 + 1) * 64 + lane) * 8];
    unsigned short* vDh0 = &VfH[((wave * 2 + 0) * 64 + lane) * 8];
    unsigned short* vDh1 = &VfH[((wave * 2 + 1) * 64 + lane) * 8];
    unsigned short* vDl0 = &VfL[((wave * 2 + 0) * 64 + lane) * 8];
    unsigned short* vDl1 = &VfL[((wave * 2 + 1) * 64 + lane) * 8];
    const size_t vrow = ((size_t)bh * 64 + wave * 16 + lm) * 2048;

    for (int jt = 0; jt < 5; ++jt) {
        const int jt0 = i0 - 128 + jt * 64;
        {
            const int jrow = jt0 + wave * 16 + lm;
            const int jrc = min(max(jrow, 0), SS - 1);
            const size_t kgb = ((size_t)(b * SS + jrc)) * DD + h * 64 + kb;
            gload16(KH + kgb,      kDh0);
            gload16(KH + kgb + 32, kDh1);
            gload16(KL + kgb,      kDl0);
            gload16(KL + kgb + 32, kDl1);
            const int j0c = min(max(jt0 + kb, 0), SS - 8);
            const int j1c = min(max(jt0 + 32 + kb, 0), SS - 8);
            gload16(VTH + vrow + j0c, vDh0);
            gload16(VTH + vrow + j1c, vDh1);
            gload16(VTL + vrow + j0c, vDl0);
            gload16(VTL + vrow + j1c, vDl1);
        }
        __syncthreads();

        #pragma unroll
        for (int js = 0; js < 4; ++js) {
            const int j0 = js * 16;
            const u16x8 bK0h = *(const u16x8*)&KfH[((js * 2 + 0) * 64 + lane) * 8];
            const u16x8 bK0l = *(const u16x8*)&KfL[((js * 2 + 0) * 64 + lane) * 8];
            const u16x8 bK1h = *(const u16x8*)&KfH[((js * 2 + 1) * 64 + lane) * 8];
            const u16x8 bK1l = *(const u16x8*)&KfL[((js * 2 + 1) * 64 + lane) * 8];
            f32x4 s = {0.f, 0.f, 0.f, 0.f};
            s = mfma16(aQ0h, bK0h, s);
            s = mfma16(aQ0h, bK0l, s);
            s = mfma16(aQ0l, bK0h, s);
            s = mfma16(aQ1h, bK1h, s);
            s = mfma16(aQ1h, bK1l, s);
            s = mfma16(aQ1l, bK1h, s);
            const int jg = jt0 + j0 + lm;
            const int iq = i0 + wave * 16 + lq * 4;
            #pragma unroll
            for (int r = 0; r < 4; ++r) {
                const int qi = iq + r;
                const bool in = (jg >= 0) && (jg < SS) &&
                                (jg >= qi - HWIN) && (jg <= qi + HWIN);
                const float w = in ? (__expf(s[r] * 0.125f) - 1.0f) : 0.0f;
                dacc[r] += w;
                unsigned short wh, wl;
                split_bf(w, wh, wl);
                Swh[wave * 16 + lq * 4 + r][j0 + lm] = wh;
                Swl[wave * 16 + lq * 4 + r][j0 + lm] = wl;
            }
        }
        __syncthreads();

        const u16x8 aP0h = *(const u16x8*)&Swh[wave * 16 + lm][kb];
        const u16x8 aP0l = *(const u16x8*)&Swl[wave * 16 + lm][kb];
        const u16x8 aP1h = *(const u16x8*)&Swh[wave * 16 + lm][kb + 32];
        const u16x8 aP1l = *(const u16x8*)&Swl[wave * 16 + lm][kb + 32];
        #pragma unroll
        for (int s4 = 0; s4 < 4; ++s4) {
            const u16x8 bV0h = *(const u16x8*)&VfH[((s4 * 2 + 0) * 64 + lane) * 8];
            const u16x8 bV0l = *(const u16x8*)&VfL[((s4 * 2 + 0) * 64 + lane) * 8];
            const u16x8 bV1h = *(const u16x8*)&VfH[((s4 * 2 + 1) * 64 + lane) * 8];
            const u16x8 bV1l = *(const u16x8*)&VfL[((s4 * 2 + 1) * 64 + lane) * 8];
            oacc[s4] = mfma16(aP0h, bV0h, oacc[s4]);
            oacc[s4] = mfma16(aP0l, bV0h, oacc[s4]);
            oacc[s4] = mfma16(aP0h, bV0l, oacc[s4]);
            oacc[s4] = mfma16(aP1h, bV1h, oacc[s4]);
            oacc[s4] = mfma16(aP1l, bV1h, oacc[s4]);
            oacc[s4] = mfma16(aP1h, bV1l, oacc[s4]);
        }
        __syncthreads();
    }

    #pragma unroll
    for (int r = 0; r < 4; ++r) {
        float v = dacc[r];
        v += __shfl_xor(v, 1);
        v += __shfl_xor(v, 2);
        v += __shfl_xor(v, 4);
        v += __shfl_xor(v, 8);
        dacc[r] = v + 2048.0f;
    }

    #pragma unroll
    for (int s4 = 0; s4 < 4; ++s4) {
        const float vsv = VS[bh * 64 + s4 * 16 + lm];
        #pragma unroll
        for (int r = 0; r < 4; ++r) {
            const int qrow = i0 + wave * 16 + lq * 4 + r;
            const float x = (oacc[s4][r] + vsv) / dacc[r];
            unsigned short xh, xl;
            split_bf(x, xh, xl);
            const size_t ix = ((size_t)(b * SS + qrow)) * DD + h * 64 + s4 * 16 + lm;
            XH[ix] = xh;
            XL[ix] = xl;
        }
    }
}

// ---------------------------------------------------------------------------
extern "C" void kernel_launch(void* const* d_in, const int* in_sizes, int n_in,
                              void* d_out, int out_size, void* d_ws, size_t ws_size,
                              hipStream_t stream)
{
    const float* query  = (const float*)d_in[0];
    const float* key_in = (const float*)d_in[1];
    const float* value  = (const float*)d_in[2];
    const float* Wq = (const float*)d_in[3]; const float* bq = (const float*)d_in[4];
    const float* Wk = (const float*)d_in[5]; const float* bk = (const float*)d_in[6];
    const float* Wv = (const float*)d_in[7]; const float* bv = (const float*)d_in[8];
    const float* Wo = (const float*)d_in[9]; const float* bo = (const float*)d_in[10];

    unsigned short* wsb = (unsigned short*)d_ws;
    unsigned short* QH  = wsb;                 // proj outputs (z=0,1 row-major)
    unsigned short* QL  = wsb + 2097152;
    unsigned short* KH  = wsb + 4194304;
    unsigned short* KL  = wsb + 6291456;
    unsigned short* VTH = wsb + 8388608;       // V transposed [bh][d][s]
    unsigned short* VTL = wsb + 10485760;
    unsigned short* XH  = wsb + 12582912;
    unsigned short* XL  = wsb + 14680064;
    unsigned short* WP  = wsb + 16777216;      // paired Wq/Wk/Wv
    unsigned short* WoP = wsb + 18350080;      // paired Wo
    float* part = (float*)((char*)d_ws + 62914560);
    float* VSp  = (float*)((char*)d_ws + 63045632);

    castW<<<512, 256, 0, stream>>>(Wq, Wk, Wv, Wo, WP, WoP);

    proj_gemm<<<1536, 256, 0, stream>>>(
        query, key_in, value, WP, bq, bk, bv, QH, VTH, VTL);

    vsum_stage1<<<dim3(16, 32), 256, 0, stream>>>(VTH, VTL, part);
    vsum_stage2<<<16, 64, 0, stream>>>(part, VSp);

    attn_mfma<<<512, 256, 0, stream>>>(
        QH, QL, KH, KL, VTH, VTL, VSp, XH, XL);

    out_gemm<<<512, 256, 0, stream>>>(XH, XL, WoP, bo, (float*)d_out);
}

// Round 13
// 168.692 us; speedup vs baseline: 1.0941x; 1.0941x over previous
//
#include <hip/hip_runtime.h>
#include <hip/hip_bf16.h>

#define SS 2048
#define DD 512
#define HWIN 128

typedef __bf16 bf16x8 __attribute__((ext_vector_type(8)));
typedef unsigned short u16x8 __attribute__((ext_vector_type(8)));
typedef float f32x4 __attribute__((ext_vector_type(4)));

__device__ __forceinline__ unsigned short f2bf(float x) {
    unsigned u = __builtin_bit_cast(unsigned, x);
    return (unsigned short)((u + 0x7fffu + ((u >> 16) & 1u)) >> 16);
}
__device__ __forceinline__ float bf2f(unsigned short s) {
    unsigned u = ((unsigned)s) << 16;
    return __builtin_bit_cast(float, u);
}
__device__ __forceinline__ void split_bf(float x, unsigned short& h, unsigned short& l) {
    h = f2bf(x);
    l = f2bf(x - bf2f(h));
}
__device__ __forceinline__ void split8(float4 f0, float4 f1, u16x8& h, u16x8& l) {
    const float vals[8] = {f0.x, f0.y, f0.z, f0.w, f1.x, f1.y, f1.z, f1.w};
    #pragma unroll
    for (int i = 0; i < 8; ++i) {
        unsigned short hh, ll;
        split_bf(vals[i], hh, ll);
        h[i] = hh;
        l[i] = ll;
    }
}
__device__ __forceinline__ f32x4 mfma16(u16x8 a, u16x8 b, f32x4 c) {
    return __builtin_amdgcn_mfma_f32_16x16x32_bf16(
        __builtin_bit_cast(bf16x8, a), __builtin_bit_cast(bf16x8, b), c, 0, 0, 0);
}
// Direct global -> LDS DMA, 16 B per lane (dest = wave-uniform base + lane*16).
__device__ __forceinline__ void gload16(const unsigned short* g, unsigned short* l) {
    __builtin_amdgcn_global_load_lds(
        (const __attribute__((address_space(1))) unsigned int*)g,
        (__attribute__((address_space(3))) unsigned int*)l, 16, 0, 0);
}

// ---------------------------------------------------------------------------
// Cast Wq,Wk,Wv -> WP (paired hi/lo bf16) and Wo -> WoP.
// ---------------------------------------------------------------------------
__global__ __launch_bounds__(256) void castW(
    const float* __restrict__ wq, const float* __restrict__ wk,
    const float* __restrict__ wv, const float* __restrict__ wo,
    unsigned short* __restrict__ WP, unsigned short* __restrict__ WoP)
{
    const size_t e0 = ((size_t)blockIdx.x * 256 + threadIdx.x) * 8;
    const float* src; size_t off; unsigned short* dst;
    if      (e0 < 262144) { src = wq; off = e0;          dst = WP + 2 * e0; }
    else if (e0 < 524288) { src = wk; off = e0 - 262144; dst = WP + 2 * e0; }
    else if (e0 < 786432) { src = wv; off = e0 - 524288; dst = WP + 2 * e0; }
    else                  { src = wo; off = e0 - 786432; dst = WoP + 2 * (e0 - 786432); }
    u16x8 h, l;
    split8(*(const float4*)(src + off), *(const float4*)(src + off + 4), h, l);
    *(u16x8*)(dst)     = h;
    *(u16x8*)(dst + 8) = l;
}

// ---------------------------------------------------------------------------
// proj GEMM (R10 config: 128x64 tile, BK=32, grid 768): C = A@W.T + bias.
// A fp32 split in-register -> LDS; W paired bf16 DMA'd. Split-bf16 3-product.
// z<2: write hi-only (QH/KH — attention is bf16 now). z==2: write V
// transposed, hi AND lo (lo needed only by the exact V column-sum).
// ---------------------------------------------------------------------------
__global__ __launch_bounds__(256) void proj_gemm(
    const float* __restrict__ q, const float* __restrict__ k, const float* __restrict__ v,
    const unsigned short* __restrict__ WP,
    const float* __restrict__ bq, const float* __restrict__ bk, const float* __restrict__ bv,
    unsigned short* __restrict__ base,
    unsigned short* __restrict__ VTH, unsigned short* __restrict__ VTL)
{
    const int d = blockIdx.x;
    const int hi = d >> 6, low = d & 63;
    const int x = low >> 3, rsw = low & 7;
    const int g = hi * 8 + rsw;            // 0..95
    const int y = g / 3, z = g - y * 3;

    const float* A = (z == 0) ? q : ((z == 1) ? k : v);
    const unsigned short* Wp = WP + (size_t)z * 524288;
    const float* bias = (z == 0) ? bq : ((z == 1) ? bk : bv);
    unsigned short* OH = base + (size_t)z * 4194304;

    const int m0 = y * 128, n0 = x * 64;

    __shared__ unsigned short Ah[8 * 64 * 8], Al[8 * 64 * 8];
    __shared__ unsigned short Bh[4 * 64 * 8], Bl[4 * 64 * 8];

    const int tid = threadIdx.x, wave = tid >> 6, lane = tid & 63;
    const int lm = lane & 15, lq = lane >> 4;
    const int wm = wave >> 1, wn = wave & 1;
    const int kb = lq * 8;

    f32x4 acc[4][2] = {};

    const int ar0 = m0 + (wave * 2 + 0) * 16 + lm;
    const int ar1 = m0 + (wave * 2 + 1) * 16 + lm;
    const int br  = n0 + wave * 16 + lm;

    unsigned short* aD0h = &Ah[((wave * 2 + 0) * 64 + lane) * 8];
    unsigned short* aD1h = &Ah[((wave * 2 + 1) * 64 + lane) * 8];
    unsigned short* aD0l = &Al[((wave * 2 + 0) * 64 + lane) * 8];
    unsigned short* aD1l = &Al[((wave * 2 + 1) * 64 + lane) * 8];
    unsigned short* bDh  = &Bh[(wave * 64 + lane) * 8];
    unsigned short* bDl  = &Bl[(wave * 64 + lane) * 8];

    for (int k0 = 0; k0 < 512; k0 += 32) {
        const float* p0 = A + (size_t)ar0 * 512 + k0 + kb;
        const float4 f00 = *(const float4*)p0, f01 = *(const float4*)(p0 + 4);
        const float* p1 = A + (size_t)ar1 * 512 + k0 + kb;
        const float4 f10 = *(const float4*)p1, f11 = *(const float4*)(p1 + 4);

        __syncthreads();                 // prev iteration's frag reads done
        u16x8 a0h, a0l, a1h, a1l;
        split8(f00, f01, a0h, a0l);
        split8(f10, f11, a1h, a1l);
        *(u16x8*)aD0h = a0h; *(u16x8*)aD0l = a0l;
        *(u16x8*)aD1h = a1h; *(u16x8*)aD1l = a1l;
        {
            const unsigned short* pw = Wp + 2 * ((size_t)br * 512 + k0 + kb);
            gload16(pw,     bDh);
            gload16(pw + 8, bDl);
        }
        __syncthreads();                 // staging visible (lds + vmcnt)

        u16x8 afh[4], afl[4], bfh[2], bfl[2];
        #pragma unroll
        for (int i = 0; i < 4; ++i) {
            afh[i] = *(const u16x8*)&Ah[((wm * 4 + i) * 64 + lane) * 8];
            afl[i] = *(const u16x8*)&Al[((wm * 4 + i) * 64 + lane) * 8];
        }
        #pragma unroll
        for (int j = 0; j < 2; ++j) {
            bfh[j] = *(const u16x8*)&Bh[((wn * 2 + j) * 64 + lane) * 8];
            bfl[j] = *(const u16x8*)&Bl[((wn * 2 + j) * 64 + lane) * 8];
        }
        #pragma unroll
        for (int i = 0; i < 4; ++i)
            #pragma unroll
            for (int j = 0; j < 2; ++j) {
                acc[i][j] = mfma16(afh[i], bfh[j], acc[i][j]);
                acc[i][j] = mfma16(afh[i], bfl[j], acc[i][j]);
                acc[i][j] = mfma16(afl[i], bfh[j], acc[i][j]);
            }
    }

    #pragma unroll
    for (int i = 0; i < 4; ++i)
        #pragma unroll
        for (int j = 0; j < 2; ++j) {
            const int col = n0 + (wn * 2 + j) * 16 + lm;
            const float bv_ = bias[col];
            #pragma unroll
            for (int r = 0; r < 4; ++r) {
                const int row = m0 + (wm * 4 + i) * 16 + lq * 4 + r;
                const float vv = acc[i][j][r] + bv_;
                unsigned short hh, ll;
                split_bf(vv, hh, ll);
                if (z == 2) {
                    const size_t vix =
                        (((size_t)(row >> 11) * 8 + (col >> 6)) * 64 + (col & 63)) * 2048
                        + (row & 2047);
                    VTH[vix] = hh;
                    VTL[vix] = ll;
                } else {
                    OH[(size_t)row * 512 + col] = hh;   // hi only
                }
            }
        }
}

// ---------------------------------------------------------------------------
// out GEMM, BK=64: 64x64 tile, grid 512, full DMA staging, split-bf16 (kept:
// final dot gets the insurance).
// ---------------------------------------------------------------------------
__global__ __launch_bounds__(256) void out_gemm(
    const unsigned short* __restrict__ XHg, const unsigned short* __restrict__ XLg,
    const unsigned short* __restrict__ WoP, const float* __restrict__ bo,
    float* __restrict__ O)
{
    const int gid = blockIdx.x;            // 0..511
    const int rr = gid & 7, hi = gid >> 3;
    const int nblk = hi & 7, mhi = hi >> 3;
    const int mblk = mhi * 8 + rr;         // 0..63
    const int m0 = mblk * 64, n0 = nblk * 64;

    __shared__ unsigned short Ah[8 * 64 * 8], Al[8 * 64 * 8];
    __shared__ unsigned short Bh[8 * 64 * 8], Bl[8 * 64 * 8];

    const int tid = threadIdx.x, wave = tid >> 6, lane = tid & 63;
    const int lm = lane & 15, lq = lane >> 4;
    const int kb = lq * 8;

    f32x4 acc[4] = {};

    const int arow = m0 + wave * 16 + lm;
    const int brow = n0 + wave * 16 + lm;

    for (int k0 = 0; k0 < 512; k0 += 64) {
        __syncthreads();
        #pragma unroll
        for (int s = 0; s < 2; ++s) {
            gload16(XHg + (size_t)arow * 512 + k0 + s * 32 + kb,
                    &Ah[((s * 4 + wave) * 64 + lane) * 8]);
            gload16(XLg + (size_t)arow * 512 + k0 + s * 32 + kb,
                    &Al[((s * 4 + wave) * 64 + lane) * 8]);
            const unsigned short* pw = WoP + 2 * ((size_t)brow * 512 + k0 + s * 32 + kb);
            gload16(pw,     &Bh[((s * 4 + wave) * 64 + lane) * 8]);
            gload16(pw + 8, &Bl[((s * 4 + wave) * 64 + lane) * 8]);
        }
        __syncthreads();

        #pragma unroll
        for (int s = 0; s < 2; ++s) {
            const u16x8 a_h = *(const u16x8*)&Ah[((s * 4 + wave) * 64 + lane) * 8];
            const u16x8 a_l = *(const u16x8*)&Al[((s * 4 + wave) * 64 + lane) * 8];
            #pragma unroll
            for (int j = 0; j < 4; ++j) {
                const u16x8 b_h = *(const u16x8*)&Bh[((s * 4 + j) * 64 + lane) * 8];
                const u16x8 b_l = *(const u16x8*)&Bl[((s * 4 + j) * 64 + lane) * 8];
                acc[j] = mfma16(a_h, b_h, acc[j]);
                acc[j] = mfma16(a_h, b_l, acc[j]);
                acc[j] = mfma16(a_l, b_h, acc[j]);
            }
        }
    }

    #pragma unroll
    for (int j = 0; j < 4; ++j) {
        const int col = n0 + j * 16 + lm;
        const float bv_ = bo[col];
        #pragma unroll
        for (int r = 0; r < 4; ++r) {
            const int row = m0 + wave * 16 + lq * 4 + r;
            O[(size_t)row * 512 + col] = acc[j][r] + bv_;
        }
    }
}

// ---------------------------------------------------------------------------
// V column sums from VT layout (hi+lo: exact). Two-stage.
// ---------------------------------------------------------------------------
__global__ __launch_bounds__(256) void vsum_stage1(
    const unsigned short* __restrict__ VTH, const unsigned short* __restrict__ VTL,
    float* __restrict__ partial)
{
    const int bh = blockIdx.x, c = blockIdx.y;
    const int t = threadIdx.x, dd = t & 63, g = t >> 6;
    __shared__ float p[4][64];
    const size_t rb = ((size_t)bh * 64 + dd) * 2048 + c * 64 + g * 16;
    const u16x8 h0 = *(const u16x8*)(VTH + rb), h1 = *(const u16x8*)(VTH + rb + 8);
    const u16x8 l0 = *(const u16x8*)(VTL + rb), l1 = *(const u16x8*)(VTL + rb + 8);
    float acc = 0.f;
    #pragma unroll
    for (int i = 0; i < 8; ++i) acc += bf2f(h0[i]) + bf2f(l0[i]);
    #pragma unroll
    for (int i = 0; i < 8; ++i) acc += bf2f(h1[i]) + bf2f(l1[i]);
    p[g][dd] = acc;
    __syncthreads();
    if (t < 64)
        partial[((size_t)bh * 32 + c) * 64 + t] =
            p[0][t] + p[1][t] + p[2][t] + p[3][t];
}

__global__ __launch_bounds__(64) void vsum_stage2(
    const float* __restrict__ partial, float* __restrict__ VS)
{
    const int bh = blockIdx.x, dd = threadIdx.x;
    float acc = 0.f;
    #pragma unroll 8
    for (int c = 0; c < 32; ++c)
        acc += partial[((size_t)bh * 32 + c) * 64 + dd];
    VS[bh * 64 + dd] = acc;
}

// ---------------------------------------------------------------------------
// PLAIN-bf16 MFMA sliding-window attention (error budget: bf16 here costs
// ~1e-4 tail on the output because all errors divide by the 2048 denom).
// K and V^T hi fragments DMA'd global->LDS with clamp-and-mask.
//   x = [ sum_win (e^s - 1) v + VS ] / ( 2048 + sum_win (e^s - 1) )
// X output still split (hi+lo) for the split out_gemm.
// ---------------------------------------------------------------------------
__global__ __launch_bounds__(256) void attn_mfma(
    const unsigned short* __restrict__ QH, const unsigned short* __restrict__ KH,
    const unsigned short* __restrict__ VTH, const float* __restrict__ VS,
    unsigned short* __restrict__ XH, unsigned short* __restrict__ XL)
{
    const int dblk = blockIdx.x;
    const int bhi = dblk >> 8, blow = dblk & 255;
    const int xblk = blow >> 3, rrs = blow & 7;
    const int bh = bhi * 8 + rrs;        // 0..15
    const int h = bh & 7, b = bh >> 3;
    const int i0 = xblk * 64;
    const int tid = threadIdx.x, wave = tid >> 6, lane = tid & 63;
    const int lm = lane & 15, lq = lane >> 4;
    const int kb = lq * 8;

    __shared__ unsigned short KfH[8 * 64 * 8];   // [js*2+c][lane][8]
    __shared__ unsigned short VfH[8 * 64 * 8];   // [s4*2+c][lane][8]
    __shared__ unsigned short Swh[64][72];       // [q][j]

    const size_t qoff = ((size_t)(b * SS + i0 + wave * 16 + lm)) * DD + h * 64 + kb;
    const u16x8 aQ0h = *(const u16x8*)(QH + qoff);
    const u16x8 aQ1h = *(const u16x8*)(QH + qoff + 32);

    f32x4 oacc[4] = {};
    float dacc[4] = {0.f, 0.f, 0.f, 0.f};

    unsigned short* kDh0 = &KfH[((wave * 2 + 0) * 64 + lane) * 8];
    unsigned short* kDh1 = &KfH[((wave * 2 + 1) * 64 + lane) * 8];
    unsigned short* vDh0 = &VfH[((wave * 2 + 0) * 64 + lane) * 8];
    unsigned short* vDh1 = &VfH[((wave * 2 + 1) * 64 + lane) * 8];
    const size_t vrow = ((size_t)bh * 64 + wave * 16 + lm) * 2048;

    for (int jt = 0; jt < 5; ++jt) {
        const int jt0 = i0 - 128 + jt * 64;
        {
            const int jrow = jt0 + wave * 16 + lm;
            const int jrc = min(max(jrow, 0), SS - 1);
            const size_t kgb = ((size_t)(b * SS + jrc)) * DD + h * 64 + kb;
            gload16(KH + kgb,      kDh0);
            gload16(KH + kgb + 32, kDh1);
            const int j0c = min(max(jt0 + kb, 0), SS - 8);
            const int j1c = min(max(jt0 + 32 + kb, 0), SS - 8);
            gload16(VTH + vrow + j0c, vDh0);
            gload16(VTH + vrow + j1c, vDh1);
        }
        __syncthreads();

        #pragma unroll
        for (int js = 0; js < 4; ++js) {
            const int j0 = js * 16;
            const u16x8 bK0h = *(const u16x8*)&KfH[((js * 2 + 0) * 64 + lane) * 8];
            const u16x8 bK1h = *(const u16x8*)&KfH[((js * 2 + 1) * 64 + lane) * 8];
            f32x4 s = {0.f, 0.f, 0.f, 0.f};
            s = mfma16(aQ0h, bK0h, s);
            s = mfma16(aQ1h, bK1h, s);
            const int jg = jt0 + j0 + lm;
            const int iq = i0 + wave * 16 + lq * 4;
            #pragma unroll
            for (int r = 0; r < 4; ++r) {
                const int qi = iq + r;
                const bool in = (jg >= 0) && (jg < SS) &&
                                (jg >= qi - HWIN) && (jg <= qi + HWIN);
                const float w = in ? (__expf(s[r] * 0.125f) - 1.0f) : 0.0f;
                dacc[r] += w;
                Swh[wave * 16 + lq * 4 + r][j0 + lm] = f2bf(w);
            }
        }
        __syncthreads();

        const u16x8 aP0h = *(const u16x8*)&Swh[wave * 16 + lm][kb];
        const u16x8 aP1h = *(const u16x8*)&Swh[wave * 16 + lm][kb + 32];
        #pragma unroll
        for (int s4 = 0; s4 < 4; ++s4) {
            const u16x8 bV0h = *(const u16x8*)&VfH[((s4 * 2 + 0) * 64 + lane) * 8];
            const u16x8 bV1h = *(const u16x8*)&VfH[((s4 * 2 + 1) * 64 + lane) * 8];
            oacc[s4] = mfma16(aP0h, bV0h, oacc[s4]);
            oacc[s4] = mfma16(aP1h, bV1h, oacc[s4]);
        }
        __syncthreads();
    }

    #pragma unroll
    for (int r = 0; r < 4; ++r) {
        float v = dacc[r];
        v += __shfl_xor(v, 1);
        v += __shfl_xor(v, 2);
        v += __shfl_xor(v, 4);
        v += __shfl_xor(v, 8);
        dacc[r] = v + 2048.0f;
    }

    #pragma unroll
    for (int s4 = 0; s4 < 4; ++s4) {
        const float vsv = VS[bh * 64 + s4 * 16 + lm];
        #pragma unroll
        for (int r = 0; r < 4; ++r) {
            const int qrow = i0 + wave * 16 + lq * 4 + r;
            const float x = (oacc[s4][r] + vsv) / dacc[r];
            unsigned short xh, xl;
            split_bf(x, xh, xl);
            const size_t ix = ((size_t)(b * SS + qrow)) * DD + h * 64 + s4 * 16 + lm;
            XH[ix] = xh;
            XL[ix] = xl;
        }
    }
}

// ---------------------------------------------------------------------------
extern "C" void kernel_launch(void* const* d_in, const int* in_sizes, int n_in,
                              void* d_out, int out_size, void* d_ws, size_t ws_size,
                              hipStream_t stream)
{
    const float* query  = (const float*)d_in[0];
    const float* key_in = (const float*)d_in[1];
    const float* value  = (const float*)d_in[2];
    const float* Wq = (const float*)d_in[3]; const float* bq = (const float*)d_in[4];
    const float* Wk = (const float*)d_in[5]; const float* bk = (const float*)d_in[6];
    const float* Wv = (const float*)d_in[7]; const float* bv = (const float*)d_in[8];
    const float* Wo = (const float*)d_in[9]; const float* bo = (const float*)d_in[10];

    unsigned short* wsb = (unsigned short*)d_ws;
    unsigned short* QH  = wsb;                 // z=0 output (hi only)
    unsigned short* KH  = wsb + 4194304;       // z=1 output (hi only)
    unsigned short* VTH = wsb + 8388608;       // V transposed hi [bh][d][s]
    unsigned short* VTL = wsb + 10485760;      // V transposed lo (vsum only)
    unsigned short* XH  = wsb + 12582912;
    unsigned short* XL  = wsb + 14680064;
    unsigned short* WP  = wsb + 16777216;      // paired Wq/Wk/Wv
    unsigned short* WoP = wsb + 18350080;      // paired Wo
    float* part = (float*)((char*)d_ws + 62914560);
    float* VSp  = (float*)((char*)d_ws + 63045632);

    castW<<<512, 256, 0, stream>>>(Wq, Wk, Wv, Wo, WP, WoP);

    proj_gemm<<<768, 256, 0, stream>>>(
        query, key_in, value, WP, bq, bk, bv, QH, VTH, VTL);

    vsum_stage1<<<dim3(16, 32), 256, 0, stream>>>(VTH, VTL, part);
    vsum_stage2<<<16, 64, 0, stream>>>(part, VSp);

    attn_mfma<<<512, 256, 0, stream>>>(QH, KH, VTH, VSp, XH, XL);

    out_gemm<<<512, 256, 0, stream>>>(XH, XL, WoP, bo, (float*)d_out);
}